// Round 8
// baseline (99.618 us; speedup 1.0000x reference)
//
#include <hip/hip_runtime.h>
#include <hip/hip_bf16.h>

typedef __bf16 bf16;
typedef __bf16 bf16x4 __attribute__((ext_vector_type(4)));
typedef __bf16 bf16x8 __attribute__((ext_vector_type(8)));
typedef float f32x4 __attribute__((ext_vector_type(4)));

#define GLOBAL_AS __attribute__((address_space(1)))
#define LDS_AS __attribute__((address_space(3)))

__device__ __forceinline__ void gload_lds16(const void* g, void* l) {
  __builtin_amdgcn_global_load_lds((const GLOBAL_AS void*)g, (LDS_AS void*)l, 16, 0, 0);
}

// ---- prep A (R7-verified): token f32 -> fragment-major A_pack bf16 (4 MB) ----
// g = b*256 + kb*16 + rgrp*4 + mf; elem g*512 + lane*8 + e
// content: token[b*256 + rgrp*64 + mf*16 + (lane&15)][kb*32 + (lane>>4)*8 + e]
__global__ __launch_bounds__(256) void pack_a_k(const float* __restrict__ t,
                                                bf16* __restrict__ o) {
  int g = blockIdx.x * 4 + (threadIdx.x >> 6);
  int lane = threadIdx.x & 63;
  int mf = g & 3, rg = (g >> 2) & 3, kb = (g >> 4) & 15, b = g >> 8;
  int m = (b << 8) + (rg << 6) + (mf << 4) + (lane & 15);
  int k = (kb << 5) + ((lane >> 4) << 3);
  const float* src = t + (size_t)m * 512 + k;
  f32x4 v0 = *(const f32x4*)src;
  f32x4 v1 = *(const f32x4*)(src + 4);
  bf16x8 p;
  p[0] = (bf16)v0[0]; p[1] = (bf16)v0[1]; p[2] = (bf16)v0[2]; p[3] = (bf16)v0[3];
  p[4] = (bf16)v1[0]; p[5] = (bf16)v1[1]; p[6] = (bf16)v1[2]; p[7] = (bf16)v1[3];
  *(bf16x8*)(o + ((size_t)g << 9) + (lane << 3)) = p;
}

// ---- prep B (R7-verified, fixed): W f32 -> fragment-major B_pack bf16 (16 MB) ----
// frag (jg, kb, nf): elem ((jg*16+kb)*4+nf)*512 + lane*8 + e
// content: W[kb*32 + (lane>>4)*8 + e][jg*64 + nf*16 + (lane&15)]
__global__ __launch_bounds__(256) void pack_b_k(const float* __restrict__ wsrc,
                                                bf16* __restrict__ o) {
  __shared__ float tile[32][65];
  int tileid = blockIdx.x;            // 4096 = jg(256) x kb(16)
  int kb = tileid & 15, jg = tileid >> 4;
  int k0 = kb << 5, j0 = jg << 6;
  int tid = threadIdx.x;
  {
    int r = tid >> 3, c8 = (tid & 7) << 3;
    const float* src = wsrc + (size_t)(k0 + r) * 16384 + j0 + c8;
    f32x4 a = *(const f32x4*)src;
    f32x4 b2 = *(const f32x4*)(src + 4);
    *(f32x4*)&tile[r][c8] = a;
    *(f32x4*)&tile[r][c8 + 4] = b2;
  }
  __syncthreads();
  int lr = tid & 15, khi = (tid >> 4) & 3, nf = tid >> 6;
  int j = (nf << 4) + lr, kk = khi << 3;
  bf16x8 p;
#pragma unroll
  for (int e = 0; e < 8; ++e) p[e] = (bf16)tile[kk + e][j];
  *(bf16x8*)(o + ((size_t)(((jg << 4) + kb) * 4 + nf) << 9) + ((tid & 63) << 3)) = p;
}

// ---- fused main: GEMM1 256x128xK512, 4 waves x (128x64) tiles (42.7 FLOP/B),
//      fragment-linear LDS (0-conflict), BK=32 double-buffer (48 KB -> 2 blk/CU),
//      m97 2-phase drain schedule; + bias + silu + rope + GEMM2 ----
// grid (hg=128, b=16), 256 threads = 4 waves: wm = w>>1 (128-row grp), wn = w&1.
__global__ __launch_bounds__(256, 2) void fused_main_k(
    const bf16* __restrict__ Ap, const bf16* __restrict__ Bp,
    const float* __restrict__ bias, float* __restrict__ out) {
  __shared__ char smem[65536];
  const int tid = threadIdx.x;
  const int lane = tid & 63;
  const int w = tid >> 6;
  const int wm = w >> 1;   // 0..1
  const int wn = w & 1;    // 0..1
  const int b = blockIdx.y;
  const int hg = blockIdx.x;
  const int j0 = hg << 7;

  const bf16* Abase = Ap + ((size_t)b << 17);  // slab(b,t) = +t*8192 elems (16 KB)

  f32x4 acc[8][4] = {};

  // stage A-slab t (16 KB) + B-slab t (8 KB) into buffer d (0/1)
#define STAGE(t_, d_) do { \
    _Pragma("unroll") \
    for (int i_ = 0; i_ < 4; ++i_) { \
      int c_ = i_ * 256 + tid; \
      gload_lds16(Abase + ((size_t)(t_) << 13) + (c_ << 3), \
                  smem + (d_) * 24576 + (c_ << 4)); \
    } \
    _Pragma("unroll") \
    for (int j_ = 0; j_ < 2; ++j_) { \
      gload_lds16(Bp + (((size_t)(2 * hg + j_) * 16 + (t_)) << 11) + (tid << 3), \
                  smem + (d_) * 24576 + 16384 + j_ * 4096 + (tid << 4)); \
    } \
  } while (0)

  STAGE(0, 0);
  __syncthreads();

  // ---- K-loop: 16 steps of BK=32, double-buffered, drain per step ----
#pragma unroll
  for (int t = 0; t < 16; ++t) {
    const int d = (t & 1) * 24576;
    if (t < 15) STAGE(t + 1, (t + 1) & 1);
    bf16x8 af[8], bfr[4];
#pragma unroll
    for (int mf = 0; mf < 8; ++mf)
      af[mf] = *(const bf16x8*)(smem + d + ((wm * 8 + mf) << 10) + (lane << 4));
#pragma unroll
    for (int nf = 0; nf < 4; ++nf)
      bfr[nf] = *(const bf16x8*)(smem + d + 16384 + ((wn * 4 + nf) << 10) + (lane << 4));
    __builtin_amdgcn_s_setprio(1);
#pragma unroll
    for (int mf = 0; mf < 8; ++mf)
#pragma unroll
      for (int nf = 0; nf < 4; ++nf)
        acc[mf][nf] = __builtin_amdgcn_mfma_f32_16x16x32_bf16(
            af[mf], bfr[nf], acc[mf][nf], 0, 0, 0);
    __builtin_amdgcn_s_setprio(0);
    __syncthreads();  // drains vmcnt (staged t+1) + lgkm; frees buf d for t+2
  }
#undef STAGE

  // ---- epilogue (R1-verbatim math): bias + silu + rope; k/v bf16 -> LDS [h][d][n] ----
#pragma unroll
  for (int nf = 0; nf < 4; ++nf) {
    const int col = wn * 64 + nf * 16 + (lane & 15);  // 0..127
    const int hl = col >> 5;                          // 0..3 local channel
    const int dd = lane & 15;
    const bool isk = ((nf & 1) == 0);
    const float bv = bias[j0 + col];
    float freq = 0.f, sgn = 0.f;
    if (isk) {
      const int tp = dd >> 1;
      const int hglob = (hg << 2) + hl;
      freq = exp2f((float)(hglob * 8 + tp) * (-13.287712379549449f / 4096.0f));
      sgn = (dd & 1) ? 1.0f : -1.0f;
    }
#pragma unroll
    for (int mf = 0; mf < 8; ++mf) {
      const int n0 = wm * 128 + (mf >> 2) * 64 + (mf & 3) * 16 + ((lane >> 4) << 2);
      f32x4 c = acc[mf][nf];
#pragma unroll
      for (int j = 0; j < 4; ++j) {
        float x = c[j] + bv;
        if (isk) x = x * __builtin_amdgcn_rcpf(1.0f + __expf(-x));  // silu
        c[j] = x;
      }
      if (isk) {
#pragma unroll
        for (int j = 0; j < 4; ++j) {
          float partner = __shfl_xor(c[j], 1);  // pre-update value, lockstep
          float sv, cv;
          __sincosf(freq * (float)(255 - (n0 + j)), &sv, &cv);
          c[j] = c[j] * cv + sgn * partner * sv;
        }
      }
      bf16x4 pk;
      pk[0] = (bf16)c[0]; pk[1] = (bf16)c[1]; pk[2] = (bf16)c[2]; pk[3] = (bf16)c[3];
      int byte = (isk ? 0 : 32768) + hl * 8192 + dd * 512 + n0 * 2;
      byte ^= ((dd & 7) << 4);  // bank swizzle
      *(bf16x4*)(smem + byte) = pk;
    }
  }
  __syncthreads();

  // ---- GEMM2: wave w owns channel w fully (256 n): 8 MFMAs ----
  {
    const int dd = lane & 15;
    f32x4 d2 = {0.f, 0.f, 0.f, 0.f};
#pragma unroll
    for (int kk = 0; kk < 8; ++kk) {
      const int n0 = kk * 32 + ((lane >> 4) << 3);
      int byte = w * 8192 + dd * 512 + n0 * 2;
      byte ^= ((dd & 7) << 4);
      bf16x8 ka = *(const bf16x8*)(smem + byte);           // k^T: [d][n]
      bf16x8 vb = *(const bf16x8*)(smem + 32768 + byte);   // v:   [e][n]
      d2 = __builtin_amdgcn_mfma_f32_16x16x32_bf16(ka, vb, d2, 0, 0, 0);
    }
    __syncthreads();  // all k/v reads done before partials overwrite
    float* part = (float*)smem;  // [4][256]
#pragma unroll
    for (int j = 0; j < 4; ++j) {
      int de = (((lane >> 4) << 2) + j) * 16 + dd;  // d*16+e
      part[w * 256 + de] = d2[j];
    }
  }
  __syncthreads();

  // ---- transpose-combine through LDS, coalesced f32x4 store ----
  {
    const float* part = (const float*)smem;
    f32x4 o;
#pragma unroll
    for (int ch = 0; ch < 4; ++ch) o[ch] = part[ch * 256 + tid];
    *(f32x4*)(out + (size_t)b * 131072 + (size_t)tid * 512 + hg * 4) = o;
  }
}

extern "C" void kernel_launch(void* const* d_in, const int* in_sizes, int n_in,
                              void* d_out, int out_size, void* d_ws, size_t ws_size,
                              hipStream_t stream) {
  const float* token = (const float*)d_in[0];   // (16,256,512) f32
  const float* W     = (const float*)d_in[1];   // (512,16384) f32
  const float* bias  = (const float*)d_in[2];   // (16384,) f32
  float* out = (float*)d_out;                   // (16,256,512) f32

  bf16* Apack = (bf16*)d_ws;                                    // 4 MB
  bf16* Bpack = (bf16*)((char*)d_ws + (size_t)4 * 1024 * 1024); // 16 MB

  pack_a_k<<<1024, 256, 0, stream>>>(token, Apack);
  pack_b_k<<<4096, 256, 0, stream>>>(W, Bpack);
  fused_main_k<<<dim3(128, 16), 256, 0, stream>>>(Apack, Bpack, bias, out);
}